// Round 1
// baseline (161.077 us; speedup 1.0000x reference)
//
#include <hip/hip_runtime.h>
#include <hip/hip_bf16.h>
#include <math.h>

// Problem: B=1, N=512, C=256, fp32 in/out.
// out[i,c] = sum_j softmax_j( w[i,j,c] ) * v[j,c],  w = mish(LN(Kp[j]-Qp[i])) @ W2  (+b2 cancels)
// Kp = mish(LN(feat@Wk+bk)) @ W1 + b1 ; Qp = mish(LN(feat@Wq+bq)) @ W1 ; v = feat@Wv+bv

#define N_ 512
#define C_ 256

typedef short s4v __attribute__((ext_vector_type(4)));
typedef short s8v __attribute__((ext_vector_type(8)));
typedef float f4v __attribute__((ext_vector_type(4)));

__device__ __forceinline__ unsigned short f2bf(float x) {
  union { __hip_bfloat16 h; unsigned short u; } cv;
  cv.h = __float2bfloat16(x);
  return cv.u;
}

__device__ __forceinline__ float mish_f(float x) {
  // mish(x) = x*tanh(softplus(x)) = x*(y^2-1)/(y^2+1), y = 1+e^x
  if (x > 25.f) return x;  // tanh saturated to 1.0 in fp32
  float y = 1.f + __expf(x);
  float y2 = y * y;
  return x * __fdividef(y2 - 1.f, y2 + 1.f);
}

// block (256 thr) reduction of two values, result broadcast to all threads
__device__ __forceinline__ void blockReduce2(float& a, float& b, float* red) {
  #pragma unroll
  for (int m = 1; m < 64; m <<= 1) { a += __shfl_xor(a, m); b += __shfl_xor(b, m); }
  int lane = threadIdx.x & 63, w = threadIdx.x >> 6;
  if (lane == 0) { red[w] = a; red[4 + w] = b; }
  __syncthreads();
  a = red[0] + red[1] + red[2] + red[3];
  b = red[4] + red[5] + red[6] + red[7];
  __syncthreads();
}

// ---------------- prep: dist, v, Qp, Kp (fp32) ----------------
// 128 blocks x 256 threads, 4 rows per block. Thread = output channel c.
__global__ void __launch_bounds__(256) prep_kernel(
    const float* __restrict__ feat,
    const float* __restrict__ Wq, const float* __restrict__ bq,
    const float* __restrict__ gq, const float* __restrict__ bgq,
    const float* __restrict__ Wk, const float* __restrict__ bk,
    const float* __restrict__ gk, const float* __restrict__ bgk,
    const float* __restrict__ Wv, const float* __restrict__ bv,
    const float* __restrict__ W1, const float* __restrict__ b1,
    float* __restrict__ dist, float* __restrict__ vout,
    float* __restrict__ Qp, float* __restrict__ Kp) {
  const int tid = threadIdx.x;
  const int r0 = blockIdx.x * 4;
  __shared__ float fL[4][C_];
  __shared__ float xq[4][C_];
  __shared__ float xk[4][C_];
  __shared__ float red[8];

  #pragma unroll
  for (int r = 0; r < 4; ++r) fL[r][tid] = feat[(r0 + r) * C_ + tid];
  __syncthreads();

  // dist = (sum |feat| > 0)
  {
    float a = fabsf(fL[0][tid]), b = fabsf(fL[1][tid]);
    blockReduce2(a, b, red);
    if (tid == 0) { dist[r0 + 0] = a > 0.f ? 1.f : 0.f; dist[r0 + 1] = b > 0.f ? 1.f : 0.f; }
    a = fabsf(fL[2][tid]); b = fabsf(fL[3][tid]);
    blockReduce2(a, b, red);
    if (tid == 0) { dist[r0 + 2] = a > 0.f ? 1.f : 0.f; dist[r0 + 3] = b > 0.f ? 1.f : 0.f; }
  }

  // q/k/v matmuls (fp32)
  float aq[4] = {0,0,0,0}, ak[4] = {0,0,0,0}, av[4] = {0,0,0,0};
  for (int cp = 0; cp < C_; ++cp) {
    float wq = Wq[cp * C_ + tid], wk = Wk[cp * C_ + tid], wv = Wv[cp * C_ + tid];
    #pragma unroll
    for (int r = 0; r < 4; ++r) {
      float f = fL[r][cp];
      aq[r] += f * wq; ak[r] += f * wk; av[r] += f * wv;
    }
  }
  {
    float bvv = bv[tid];
    #pragma unroll
    for (int r = 0; r < 4; ++r) vout[(r0 + r) * C_ + tid] = av[r] + bvv;
  }

  const float bqv = bq[tid], bkv = bk[tid];
  const float gqv = gq[tid], bgqv = bgq[tid], gkv = gk[tid], bgkv = bgk[tid];
  for (int r = 0; r < 4; ++r) {
    float qv = aq[r] + bqv, kv = ak[r] + bkv;
    float s1 = qv, s2 = qv * qv;
    blockReduce2(s1, s2, red);
    float mu = s1 * (1.f / C_);
    float rs = rsqrtf(s2 * (1.f / C_) - mu * mu + 1e-5f);
    xq[r][tid] = mish_f((qv - mu) * rs * gqv + bgqv);
    s1 = kv; s2 = kv * kv;
    blockReduce2(s1, s2, red);
    mu = s1 * (1.f / C_);
    rs = rsqrtf(s2 * (1.f / C_) - mu * mu + 1e-5f);
    xk[r][tid] = mish_f((kv - mu) * rs * gkv + bgkv);
  }
  __syncthreads();

  // Qp = q@W1, Kp = k@W1 + b1
  float pq[4] = {0,0,0,0}, pk[4] = {0,0,0,0};
  for (int cp = 0; cp < C_; ++cp) {
    float w1 = W1[cp * C_ + tid];
    #pragma unroll
    for (int r = 0; r < 4; ++r) { pq[r] += xq[r][cp] * w1; pk[r] += xk[r][cp] * w1; }
  }
  const float b1v = b1[tid];
  #pragma unroll
  for (int r = 0; r < 4; ++r) {
    Qp[(r0 + r) * C_ + tid] = pq[r];
    Kp[(r0 + r) * C_ + tid] = pk[r] + b1v;
  }
}

// ---------------- W2 -> bf16 fragment-linear repack ----------------
// W2f[((c16*8+ks)*64+lane)*8+h] = bf16( W2[k][c] ),
//   k = ks*32 + 16*(h>>2) + 4*(lane>>4) + (h&3),  c = c16*16 + (lane&15)
__global__ void __launch_bounds__(256) repack_kernel(
    const float* __restrict__ W2, unsigned short* __restrict__ W2f) {
  int idx = blockIdx.x * 256 + threadIdx.x;  // 65536 total
  int h = idx & 7;
  int l = (idx >> 3) & 63;
  int ks = (idx >> 9) & 7;
  int c16 = idx >> 12;
  int k = ks * 32 + ((h >> 2) << 4) + ((l >> 4) << 2) + (h & 3);
  int c = (c16 << 4) + (l & 15);
  W2f[idx] = f2bf(W2[k * C_ + c]);
}

// ---------------- main fused kernel ----------------
// 512 blocks (one per i) x 256 threads (4 waves).
// Per 16-j tile: T = mish(LN(Kp-Qp)) -> LDS (bf16, XOR-swizzled);
// w = T @ W2 via mfma_16x16x32_bf16 (B frags resident in regs);
// online softmax over j per channel c with shfl_xor(16/32) reduction.
__global__ void __launch_bounds__(256, 2) attn_kernel(
    const float* __restrict__ dist, const float* __restrict__ v,
    const float* __restrict__ Qp, const float* __restrict__ Kp,
    const unsigned short* __restrict__ W2f,
    const float* __restrict__ gw, const float* __restrict__ bw,
    float* __restrict__ out) {
  const int tid = threadIdx.x;
  const int i = blockIdx.x;
  const int lane = tid & 63, wave = tid >> 6;
  const int jg = tid >> 4;       // local j row this thread computes (T phase)
  const int g = tid & 15;        // sub-group lane
  const int c0 = g * 16;         // T phase channel base (16 channels/thread)
  const int jr = lane & 15;      // MFMA A-fragment row
  const int kg = lane >> 4;      // k-group / D-row group
  const int cch = wave * 64 + (lane & 15);  // softmax channel base (+ct*16)

  __shared__ __align__(16) unsigned short T[16 * C_];  // 8 KiB, swizzled
  __shared__ float distT[16];
  char* Tb = reinterpret_cast<char*>(T);

  const float dist_i = dist[i];

  // hoisted per-thread constants (avoid LDS bank conflicts in T phase)
  float qpr[16], gwr[16], bwr[16];
  {
    const float* qprow = Qp + i * C_ + c0;
    #pragma unroll
    for (int e = 0; e < 16; ++e) {
      qpr[e] = qprow[e];
      gwr[e] = gw[c0 + e];
      bwr[e] = bw[c0 + e];
    }
  }

  // resident B fragments: 4 ctiles x 8 ksteps (128 VGPRs)
  s8v Bfr[4][8];
  #pragma unroll
  for (int ct = 0; ct < 4; ++ct)
    #pragma unroll
    for (int ks = 0; ks < 8; ++ks)
      Bfr[ct][ks] = *reinterpret_cast<const s8v*>(
          W2f + (((((wave * 4 + ct) * 8 + ks) * 64) + lane) << 3));

  float m_[4], den[4], acc[4];
  #pragma unroll
  for (int ct = 0; ct < 4; ++ct) { m_[ct] = -INFINITY; den[ct] = 0.f; acc[ct] = 0.f; }

  for (int jt = 0; jt < N_ / 16; ++jt) {
    const int j = jt * 16 + jg;
    // ---- T phase: t[j, c0..c0+15] = mish(LN(Kp[j]-Qp[i])) ----
    const float* kpr = Kp + j * C_ + c0;
    float d[16];
    float s = 0.f, s2 = 0.f;
    #pragma unroll
    for (int e = 0; e < 16; ++e) {
      float x = kpr[e] - qpr[e];
      d[e] = x; s += x; s2 += x * x;
    }
    #pragma unroll
    for (int mk = 1; mk < 16; mk <<= 1) { s += __shfl_xor(s, mk); s2 += __shfl_xor(s2, mk); }
    float mu = s * (1.f / C_);
    float rs = rsqrtf(s2 * (1.f / C_) - mu * mu + 1e-5f);
    if (g == 0) distT[jg] = dist[j];
    s8v t0, t1;
    #pragma unroll
    for (int e = 0; e < 8; ++e)
      t0[e] = (short)f2bf(mish_f((d[e] - mu) * rs * gwr[e] + bwr[e]));
    #pragma unroll
    for (int e = 8; e < 16; ++e)
      t1[e - 8] = (short)f2bf(mish_f((d[e] - mu) * rs * gwr[e] + bwr[e]));
    const int ab = jg * 512 + g * 32;
    const int sw = (jg & 7) << 4;
    *reinterpret_cast<s8v*>(Tb + (ab ^ sw)) = t0;
    *reinterpret_cast<s8v*>(Tb + ((ab + 16) ^ sw)) = t1;
    __syncthreads();

    // ---- MFMA: w[16 x 256] = T @ W2 ----
    f4v w4[4];
    #pragma unroll
    for (int ct = 0; ct < 4; ++ct) w4[ct] = (f4v){0.f, 0.f, 0.f, 0.f};
    const int swA = (jr & 7) << 4;
    #pragma unroll
    for (int ks = 0; ks < 8; ++ks) {
      // A element h: k = ks*32 + 16*(h>>2) + 4*kg + (h&3)
      const int b0 = jr * 512 + ks * 64 + kg * 8;
      s4v lo = *reinterpret_cast<const s4v*>(Tb + (b0 ^ swA));
      s4v hi = *reinterpret_cast<const s4v*>(Tb + ((b0 + 32) ^ swA));
      s8v A;
      A[0] = lo[0]; A[1] = lo[1]; A[2] = lo[2]; A[3] = lo[3];
      A[4] = hi[0]; A[5] = hi[1]; A[6] = hi[2]; A[7] = hi[3];
      #pragma unroll
      for (int ct = 0; ct < 4; ++ct)
        w4[ct] = __builtin_amdgcn_mfma_f32_16x16x32_bf16(A, Bfr[ct][ks], w4[ct], 0, 0, 0);
    }

    // ---- online softmax + PV accumulate ----
    const int jb = jt * 16 + kg * 4;
    float dv[4];
    #pragma unroll
    for (int r = 0; r < 4; ++r) dv[r] = distT[kg * 4 + r];
    const float* vb = v + jb * C_;
    #pragma unroll
    for (int ct = 0; ct < 4; ++ct) {
      const int c = cch + ct * 16;
      float tmax = fmaxf(fmaxf(w4[ct][0], w4[ct][1]), fmaxf(w4[ct][2], w4[ct][3]));
      tmax = fmaxf(tmax, __shfl_xor(tmax, 16));
      tmax = fmaxf(tmax, __shfl_xor(tmax, 32));
      float mn = fmaxf(m_[ct], tmax);
      float corr = __expf(m_[ct] - mn);  // first tile: exp(-inf)=0
      float ps = 0.f, pv = 0.f;
      #pragma unroll
      for (int r = 0; r < 4; ++r) {
        float e = __expf(w4[ct][r] - mn) * dv[r];
        ps += e;
        pv += e * vb[r * C_ + c];
      }
      ps += __shfl_xor(ps, 16); ps += __shfl_xor(ps, 32);
      pv += __shfl_xor(pv, 16); pv += __shfl_xor(pv, 32);
      den[ct] = den[ct] * corr + ps;
      acc[ct] = acc[ct] * corr + pv;
      m_[ct] = mn;
    }
    __syncthreads();  // protect T before next tile's writes
  }

  if (kg == 0) {
    #pragma unroll
    for (int ct = 0; ct < 4; ++ct) {
      const int c = cch + ct * 16;
      float o = 0.f;
      if (dist_i > 0.f && den[ct] > 0.f) o = acc[ct] / den[ct];
      out[i * C_ + c] = o;
    }
  }
}

extern "C" void kernel_launch(void* const* d_in, const int* in_sizes, int n_in,
                              void* d_out, int out_size, void* d_ws, size_t ws_size,
                              hipStream_t stream) {
  const float* feat = (const float*)d_in[0];
  const float* Wq   = (const float*)d_in[1];
  const float* bq   = (const float*)d_in[2];
  const float* gq   = (const float*)d_in[3];
  const float* bgq  = (const float*)d_in[4];
  const float* Wk   = (const float*)d_in[5];
  const float* bk   = (const float*)d_in[6];
  const float* gk   = (const float*)d_in[7];
  const float* bgk  = (const float*)d_in[8];
  const float* Wv   = (const float*)d_in[9];
  const float* bv   = (const float*)d_in[10];
  const float* W1   = (const float*)d_in[11];
  const float* b1   = (const float*)d_in[12];
  const float* gw   = (const float*)d_in[13];
  const float* bw   = (const float*)d_in[14];
  const float* W2   = (const float*)d_in[15];
  // d_in[16] = b2 : cancels exactly in the j-softmax, unused.

  char* ws = (char*)d_ws;
  float* dist        = (float*)(ws + 0);        // 512 f32
  float* v           = (float*)(ws + 2048);     // 512*256 f32
  float* Qp          = (float*)(ws + 526336);   // 512*256 f32
  float* Kp          = (float*)(ws + 1050624);  // 512*256 f32
  unsigned short* W2f = (unsigned short*)(ws + 1574912);  // 256*256 bf16

  hipLaunchKernelGGL(prep_kernel, dim3(128), dim3(256), 0, stream,
                     feat, Wq, bq, gq, bgq, Wk, bk, gk, bgk, Wv, bv, W1, b1,
                     dist, v, Qp, Kp);
  hipLaunchKernelGGL(repack_kernel, dim3(256), dim3(256), 0, stream, W2, W2f);
  hipLaunchKernelGGL(attn_kernel, dim3(512), dim3(256), 0, stream,
                     dist, v, Qp, Kp, W2f, gw, bw, (float*)d_out);
}